// Round 1
// baseline (521.641 us; speedup 1.0000x reference)
//
#include <hip/hip_runtime.h>
#include <cmath>

typedef _Float16 h8  __attribute__((ext_vector_type(8)));
typedef _Float16 h4v __attribute__((ext_vector_type(4)));
typedef float    f4  __attribute__((ext_vector_type(4)));

#define NB  4096
#define NIN 4096
#define NNP 512
#define NP1 4096
#define NP2 8192
#define NH  2048

__device__ __forceinline__ void g2lds16(const _Float16* g, _Float16* l) {
  // async global->LDS, 16B per lane; LDS dest is wave-uniform base + lane*16
  __builtin_amdgcn_global_load_lds((const __attribute__((address_space(1))) void*)g,
                                   (__attribute__((address_space(3))) void*)l, 16, 0, 0);
}

// ---------------- pack f32 -> f16 (vectorized) ----------------
__global__ __launch_bounds__(256) void k_pack_f16(const float* __restrict__ in,
                                                  _Float16* __restrict__ out, int n4) {
  int i = blockIdx.x * 256 + threadIdx.x;
  if (i >= n4) return;
  f4 v = ((const f4*)in)[i];
  h4v o;
  o[0] = (_Float16)v[0]; o[1] = (_Float16)v[1];
  o[2] = (_Float16)v[2]; o[3] = (_Float16)v[3];
  ((h4v*)out)[i] = o;
}

// ---------------- transpose pack: out[n][k] = in[k][n] * optional mask ----------------
template<bool MASK>
__global__ __launch_bounds__(256) void k_packT(const float* __restrict__ in,
                                               const int* __restrict__ comp,
                                               _Float16* __restrict__ out, int K, int N) {
  __shared__ float tile[64][65];           // +1 pad: conflict-free transpose
  const int n0 = blockIdx.x * 64, k0 = blockIdx.y * 64;
  const int tx = threadIdx.x & 63, ty = threadIdx.x >> 6;
#pragma unroll
  for (int r = 0; r < 16; ++r) {
    int kk = r * 4 + ty;
    float v = in[(long)(k0 + kk) * N + n0 + tx];
    if (MASK) v *= (float)comp[(long)(k0 + kk) * NNP + ((n0 + tx) >> 3)];
    tile[kk][tx] = v;
  }
  __syncthreads();
#pragma unroll
  for (int r = 0; r < 16; ++r) {
    int nn = r * 4 + ty;
    out[(long)(n0 + nn) * K + k0 + tx] = (_Float16)tile[tx][nn];
  }
}

// ---------------- fp16 MFMA GEMM: C = A[M,K] * BT[N,K]^T + bias (m97 structure) ----------------
template<bool RELU>
__global__ __launch_bounds__(256) void k_gemm_bt(const _Float16* __restrict__ A,
                                                 const _Float16* __restrict__ BT,
                                                 const float* __restrict__ bias,
                                                 _Float16* __restrict__ C,
                                                 int M, int N, int K, int nbn) {
  __shared__ _Float16 As[128 * 32];
  __shared__ _Float16 Bs[128 * 32];
  const int bm = blockIdx.x / nbn, bn = blockIdx.x % nbn;
  const long m0 = (long)bm * 128, n0 = (long)bn * 128;
  const int tid = threadIdx.x, lane = tid & 63, w = tid >> 6;
  const int wm = w >> 1, wn = w & 1;           // 2x2 waves, 64x64 each
  const int lh = lane & 15, ls = lane >> 4;

  // staging geometry: wave w stages tile rows [w*32, w*32+32); 4 lanes per row
  const int srow = w * 32 + (lane >> 2);
  const int scol = (lane & 3) * 8;
  const _Float16* Ag = A + (m0 + srow) * (long)K + scol;
  const _Float16* Bg = BT + (n0 + srow) * (long)K + scol;
  _Float16* As0 = &As[(w * 32) * 32];
  _Float16* Bs0 = &Bs[(w * 32) * 32];

  f4 acc[4][4] = {};

  const int nk = K >> 5;
  for (int kt = 0; kt < nk; ++kt) {
    __syncthreads();                           // previous compute done before overwrite
    const _Float16* ag = Ag + kt * 32;
    const _Float16* bg = Bg + kt * 32;
    g2lds16(ag,                As0);
    g2lds16(ag + (long)16 * K, As0 + 16 * 32);
    g2lds16(bg,                Bs0);
    g2lds16(bg + (long)16 * K, Bs0 + 16 * 32);
    __syncthreads();                           // vmcnt(0) drained before barrier

    h8 af[4], bf[4];
#pragma unroll
    for (int m = 0; m < 4; ++m)
      af[m] = *(const h8*)&As[(wm * 64 + m * 16 + lh) * 32 + ls * 8];
#pragma unroll
    for (int n = 0; n < 4; ++n)
      bf[n] = *(const h8*)&Bs[(wn * 64 + n * 16 + lh) * 32 + ls * 8];
#pragma unroll
    for (int m = 0; m < 4; ++m)
#pragma unroll
      for (int n = 0; n < 4; ++n)
        acc[m][n] = __builtin_amdgcn_mfma_f32_16x16x32_f16(af[m], bf[n], acc[m][n], 0, 0, 0);
  }

  // epilogue: C/D layout col=lane&15, row=(lane>>4)*4+j
#pragma unroll
  for (int n = 0; n < 4; ++n) {
    const long c = n0 + wn * 64 + n * 16 + lh;
    const float bv = bias[c];
#pragma unroll
    for (int m = 0; m < 4; ++m) {
      const long r0 = m0 + wm * 64 + m * 16 + ls * 4;
#pragma unroll
      for (int j = 0; j < 4; ++j) {
        float v = acc[m][n][j] + bv;
        if (RELU) v = fmaxf(v, 0.f);
        C[(r0 + j) * (long)N + c] = (_Float16)v;
      }
    }
  }
}

// ---------------- block-diagonal GEMM2: out2[b,16p+jj] = sum_i out1[b,8p+i]*fc2w[8p+i,16p+jj] + fc2b ----------------
__global__ __launch_bounds__(256) void k_gemm2(const _Float16* __restrict__ out1,
                                               const float* __restrict__ fc2w,
                                               const float* __restrict__ fc2b,
                                               _Float16* __restrict__ out2) {
  const int b0 = (blockIdx.x >> 4) * 64;               // 64 b-rows per block
  const int p  = (blockIdx.x & 15) * 32 + (threadIdx.x & 31);  // 32 pathways per block
  const int bsub = threadIdx.x >> 5;                   // 0..7
  f4 bb0 = *(const f4*)&fc2b[p * 16 + 0];
  f4 bb1 = *(const f4*)&fc2b[p * 16 + 4];
  f4 bb2 = *(const f4*)&fc2b[p * 16 + 8];
  f4 bb3 = *(const f4*)&fc2b[p * 16 + 12];
  for (int r = 0; r < 8; ++r) {
    const int b = b0 + r * 8 + bsub;
    h8 q = *(const h8*)&out1[(long)b * NP1 + p * 8];
    f4 a0 = bb0, a1 = bb1, a2 = bb2, a3 = bb3;
#pragma unroll
    for (int i = 0; i < 8; ++i) {
      const float qi = (float)q[i];
      const f4* wr = (const f4*)&fc2w[(long)(p * 8 + i) * NP2 + p * 16];
      a0 += qi * wr[0]; a1 += qi * wr[1]; a2 += qi * wr[2]; a3 += qi * wr[3];
    }
    h8 o0, o1;
#pragma unroll
    for (int u = 0; u < 4; ++u) {
      o0[u] = (_Float16)a0[u]; o0[4 + u] = (_Float16)a1[u];
      o1[u] = (_Float16)a2[u]; o1[4 + u] = (_Float16)a3[u];
    }
    h8* dst = (h8*)&out2[(long)b * NP2 + p * 16];
    dst[0] = o0; dst[1] = o1;
  }
}

// ---------------- GEMM4 (f32) + sigmoid: one wave per batch row ----------------
__global__ __launch_bounds__(256) void k_logits(const _Float16* __restrict__ h,
                                                const float* __restrict__ w2,
                                                const float* __restrict__ b2,
                                                float* __restrict__ logits,
                                                float* __restrict__ hazards) {
  const int lane = threadIdx.x & 63;
  const int b = blockIdx.x * 4 + (threadIdx.x >> 6);
  f4 acc = {0.f, 0.f, 0.f, 0.f};
  const _Float16* hp = &h[(long)b * NH];
#pragma unroll
  for (int c4 = 0; c4 < 4; ++c4) {
    const int k0 = c4 * 512 + lane * 8;
    h8 hv = *(const h8*)&hp[k0];
#pragma unroll
    for (int u = 0; u < 8; ++u)
      acc += (float)hv[u] * *(const f4*)&w2[(long)(k0 + u) * 4];
  }
#pragma unroll
  for (int off = 32; off > 0; off >>= 1) {
#pragma unroll
    for (int u = 0; u < 4; ++u) acc[u] += __shfl_xor(acc[u], off, 64);
  }
  if (lane == 0) {
    f4 lg = acc + *(const f4*)b2;
    ((f4*)logits)[b] = lg;
    f4 hz;
#pragma unroll
    for (int u = 0; u < 4; ++u) hz[u] = 1.f / (1.f + expf(-lg[u]));
    ((f4*)hazards)[b] = hz;
  }
}

// ---------------- per-class batch-axis cumprod (scan) + first-occurrence argmax ----------------
__global__ __launch_bounds__(256) void k_final(const float* __restrict__ logits,
                                               const float* __restrict__ hazards,
                                               float* __restrict__ S,
                                               float* __restrict__ yhat) {
  const int c = blockIdx.x;   // 4 classes
  const int t = threadIdx.x;  // 256 threads x 16 rows
  __shared__ float pl[256];
  __shared__ float mv[256];
  __shared__ int   mi[256];
  float prod = 1.f;
  float best = -1e30f; int bi = 0;
  for (int i = 0; i < 16; ++i) {
    const int b = t * 16 + i;
    prod *= (1.f - hazards[b * 4 + c]);
    const float lg = logits[b * 4 + c];
    if (lg > best) { best = lg; bi = b; }   // strict > keeps first occurrence
  }
  pl[t] = prod; mv[t] = best; mi[t] = bi;
  __syncthreads();
  // Hillis-Steele inclusive scan of per-thread chunk products
  for (int off = 1; off < 256; off <<= 1) {
    float cur  = pl[t];
    float prev = (t >= off) ? pl[t - off] : 1.f;
    __syncthreads();
    pl[t] = cur * prev;
    __syncthreads();
  }
  float s = (t == 0) ? 1.f : pl[t - 1];
  for (int i = 0; i < 16; ++i) {
    const int b = t * 16 + i;
    s *= (1.f - hazards[b * 4 + c]);
    S[b * 4 + c] = s;
  }
  for (int off = 128; off > 0; off >>= 1) {
    if (t < off) {
      float ov = mv[t + off]; int oi = mi[t + off];
      if (ov > mv[t] || (ov == mv[t] && oi < mi[t])) { mv[t] = ov; mi[t] = oi; }
    }
    __syncthreads();
  }
  if (t == 0) yhat[c] = (float)mi[0];
}

extern "C" void kernel_launch(void* const* d_in, const int* in_sizes, int n_in,
                              void* d_out, int out_size, void* d_ws, size_t ws_size,
                              hipStream_t stream) {
  (void)in_sizes; (void)n_in; (void)out_size; (void)ws_size;
  const float* x    = (const float*)d_in[0];
  const float* fc1w = (const float*)d_in[1];
  const float* fc1b = (const float*)d_in[2];
  const float* fc2w = (const float*)d_in[3];
  const float* fc2b = (const float*)d_in[4];
  const float* w1   = (const float*)d_in[5];
  const float* b1   = (const float*)d_in[6];
  const float* w2   = (const float*)d_in[7];
  const float* b2   = (const float*)d_in[8];
  const int*   comp = (const int*)d_in[9];

  char* ws = (char*)d_ws;
  const size_t MB = 1024ull * 1024ull;
  // region plan (peak 160MB):
  //   [0,32M)   xh          -> dead after GEMM1 -> reused: hh [0,16M), logits [16M,16M+64K)
  //   [32M,64M) w1mT        (dead after GEMM1)
  //   [64M,96M) out1h       -> dead after GEMM2 -> reused: w1Th
  //   [96M,160M) out2h
  _Float16* xh     = (_Float16*)(ws + 0);
  _Float16* w1mT   = (_Float16*)(ws + 32 * MB);
  _Float16* out1h  = (_Float16*)(ws + 64 * MB);
  _Float16* out2h  = (_Float16*)(ws + 96 * MB);
  _Float16* w1Th   = (_Float16*)(ws + 64 * MB);
  _Float16* hh     = (_Float16*)(ws + 0);
  float*    logits = (float*)(ws + 16 * MB);
  float*    outF   = (float*)d_out;

  // 1) pack x -> fp16
  k_pack_f16<<<(NB * NIN / 4) / 256, 256, 0, stream>>>(x, xh, NB * NIN / 4);
  // 2) pack (fc1_w * mask1)^T -> fp16 [P1][IN]
  k_packT<true><<<dim3(NP1 / 64, NIN / 64), 256, 0, stream>>>(fc1w, comp, w1mT, NIN, NP1);
  // 3) GEMM1: out1 = x @ fc1w_masked + fc1_b  (fp16 out)
  k_gemm_bt<false><<<(NB / 128) * (NP1 / 128), 256, 0, stream>>>(
      xh, w1mT, fc1b, out1h, NB, NP1, NIN, NP1 / 128);
  // 4) block-diagonal GEMM2 -> out2 fp16
  k_gemm2<<<(NB / 64) * (NNP / 32), 256, 0, stream>>>(out1h, fc2w, fc2b, out2h);
  // 5) pack w1^T -> fp16 [H][P2] (overlays dead out1h)
  k_packT<false><<<dim3(NH / 64, NP2 / 64), 256, 0, stream>>>(w1, nullptr, w1Th, NP2, NH);
  // 6) GEMM3: h = relu(out2 @ w1 + b1)  (fp16 out, overlays dead xh)
  k_gemm_bt<true><<<(NB / 128) * (NH / 128), 256, 0, stream>>>(
      out2h, w1Th, b1, hh, NB, NH, NP2, NH / 128);
  // 7) logits (f32) + hazards = sigmoid(logits) -> d_out[0:16384)
  k_logits<<<NB / 4, 256, 0, stream>>>(hh, w2, b2, logits, outF);
  // 8) S = cumprod(1-hazards) over batch axis -> d_out[16384:32768); Y_hat argmax -> d_out[32768:32772)
  k_final<<<4, 256, 0, stream>>>(logits, outF, outF + NB * 4, outF + 2 * NB * 4);
}

// Round 2
// 363.582 us; speedup vs baseline: 1.4347x; 1.4347x over previous
//
#include <hip/hip_runtime.h>
#include <cmath>

typedef _Float16 h8  __attribute__((ext_vector_type(8)));
typedef _Float16 h4v __attribute__((ext_vector_type(4)));
typedef float    f4  __attribute__((ext_vector_type(4)));

#define NB  4096
#define NIN 4096
#define NNP 512
#define NP1 4096
#define NP2 8192
#define NH  2048

__device__ __forceinline__ void g2l(const void* g, void* l) {
  __builtin_amdgcn_global_load_lds((const __attribute__((address_space(1))) void*)g,
                                   (__attribute__((address_space(3))) void*)l, 16, 0, 0);
}

// ---------------- pack f32 -> f16 (vectorized) ----------------
__global__ __launch_bounds__(256) void k_pack_f16(const float* __restrict__ in,
                                                  _Float16* __restrict__ out, int n4) {
  int i = blockIdx.x * 256 + threadIdx.x;
  if (i >= n4) return;
  f4 v = ((const f4*)in)[i];
  h4v o;
  o[0] = (_Float16)v[0]; o[1] = (_Float16)v[1];
  o[2] = (_Float16)v[2]; o[3] = (_Float16)v[3];
  ((h4v*)out)[i] = o;
}

// ---------------- transpose pack: out[n][k] = in[k][n] * optional mask ----------------
template<bool MASK>
__global__ __launch_bounds__(256) void k_packT(const float* __restrict__ in,
                                               const int* __restrict__ comp,
                                               _Float16* __restrict__ out, int K, int N) {
  __shared__ float tile[64][65];
  const int n0 = blockIdx.x * 64, k0 = blockIdx.y * 64;
  const int tx = threadIdx.x & 63, ty = threadIdx.x >> 6;
#pragma unroll
  for (int r = 0; r < 16; ++r) {
    int kk = r * 4 + ty;
    float v = in[(long)(k0 + kk) * N + n0 + tx];
    if (MASK) v *= (float)comp[(long)(k0 + kk) * NNP + ((n0 + tx) >> 3)];
    tile[kk][tx] = v;
  }
  __syncthreads();
#pragma unroll
  for (int r = 0; r < 16; ++r) {
    int nn = r * 4 + ty;
    out[(long)(n0 + nn) * K + k0 + tx] = (_Float16)tile[tx][nn];
  }
}

// ---------------- 256x256 8-phase fp16 MFMA GEMM (T1+T2+T3+T4+T5) ----------------
// C = A[M,K] * BT[N,K]^T (+bias if !F32OUT); split-K partials to Cf if F32OUT.
// 8 waves (2m x 4n). Per wave: 128 rows x 64 cols, quadrant-interleaved across halves.
// LDS 128KB: buf{0,1} x { A[256][64] , B[256][64] } fp16, XOR-swizzled (row&7)<<4.
template<bool F32OUT>
__global__ __launch_bounds__(512, 1) void k_gemm8(
    const _Float16* __restrict__ A, const _Float16* __restrict__ BT,
    const float* __restrict__ bias, _Float16* __restrict__ C,
    float* __restrict__ Cf, int M, int N, int K, int nbn, int ksplit) {
  extern __shared__ char smem[];
  // bijective XCD swizzle (nwg % 8 == 0 here)
  const int nwg = gridDim.x;
  const int q = nwg >> 3, r = nwg & 7;
  const int xcd = blockIdx.x & 7, idx = blockIdx.x >> 3;
  const int wg = (xcd < r ? xcd * (q + 1) : r * (q + 1) + (xcd - r) * q) + idx;
  const int tpk = nwg / ksplit;
  const int ks = wg / tpk;
  const int rem = wg - ks * tpk;
  const int bm = rem / nbn, bn = rem % nbn;
  const long m0 = (long)bm << 8, n0 = (long)bn << 8;
  const int Ks = K / ksplit;
  const int NT = Ks >> 6;

  const int tid = threadIdx.x;
  const int lane = tid & 63, w = tid >> 6;
  const int wm = w >> 2, wn = w & 3;
  const int lh = lane & 15, ls = lane >> 4;
  const int swz = (lh & 7) << 4;

  const long sK = (long)K * 2;               // row stride in bytes
  const char* Ab = (const char*)A + m0 * sK + (long)ks * Ks * 2;
  const char* Bb = (const char*)BT + n0 * sK + (long)ks * Ks * 2;
  // staging: thread's pre-swizzled global source (swizzle on source, linear LDS dest)
  const int scb = (((tid & 7) ^ ((tid >> 3) & 7)) << 4);
  const char* AgT = Ab + (long)(tid >> 3) * sK + scb;
  const char* BgT = Bb + (long)(tid >> 3) * sK + scb;
  const long hrow64 = 64 * sK, hrow128 = 128 * sK;
  char* const lw = smem + (w << 10);         // wave-uniform LDS write base component

#define STAGE_A(buf, h, ktb) do { \
    const char* s_ = AgT + ((h) ? hrow128 : 0) + (ktb); \
    char* d_ = lw + (buf) * 65536 + (h) * 16384; \
    g2l(s_, d_); g2l(s_ + hrow64, d_ + 8192); } while (0)
#define STAGE_B(buf, h, ktb) do { \
    const char* s_ = BgT + ((h) ? hrow128 : 0) + (ktb); \
    char* d_ = lw + (buf) * 65536 + 32768 + (h) * 16384; \
    g2l(s_, d_); g2l(s_ + hrow64, d_ + 8192); } while (0)
#define LDA_(buf, qm, m, ko) \
  (*(const h8*)(smem + (buf) * 65536 + ((qm) * 128 + wm * 64 + (m) * 16 + lh) * 128 + \
                ((((ko) << 6) + (ls << 4)) ^ swz)))
#define LDB_(buf, qn, n, ko) \
  (*(const h8*)(smem + (buf) * 65536 + 32768 + ((qn) * 128 + wn * 32 + (n) * 16 + lh) * 128 + \
                ((((ko) << 6) + (ls << 4)) ^ swz)))

  f4 acc[2][4][2][2] = {};
  h8 af[4][2], bf[2][2];

  // prologue: tile 0 into buf0, issue order A0,B0,B1,A1 (vmcnt ledger depends on it)
  STAGE_A(0, 0, 0);
  STAGE_B(0, 0, 0);
  STAGE_B(0, 1, 0);
  STAGE_A(0, 1, 0);

  for (int t = 0; t < NT; ++t) {
    const int cur = t & 1, nxt = cur ^ 1;
    const bool pf = (t + 1) < NT;
    const long knext = (long)(t + 1) << 7;   // byte offset of next K-tile

    // ---- P0: quadrant (qm=0, qn=0); needs A-half0, B-half0 of tile t
    asm volatile("s_waitcnt vmcnt(4)" ::: "memory");
    __builtin_amdgcn_s_barrier();
#pragma unroll
    for (int m = 0; m < 4; ++m) { af[m][0] = LDA_(cur, 0, m, 0); af[m][1] = LDA_(cur, 0, m, 1); }
#pragma unroll
    for (int n = 0; n < 2; ++n) { bf[n][0] = LDB_(cur, 0, n, 0); bf[n][1] = LDB_(cur, 0, n, 1); }
    if (pf) STAGE_A(nxt, 0, knext);
    __builtin_amdgcn_s_setprio(1);
#pragma unroll
    for (int m = 0; m < 4; ++m)
#pragma unroll
      for (int n = 0; n < 2; ++n) {
        acc[0][m][0][n] = __builtin_amdgcn_mfma_f32_16x16x32_f16(af[m][0], bf[n][0], acc[0][m][0][n], 0, 0, 0);
        acc[0][m][0][n] = __builtin_amdgcn_mfma_f32_16x16x32_f16(af[m][1], bf[n][1], acc[0][m][0][n], 0, 0, 0);
      }
    __builtin_amdgcn_s_setprio(0);

    // ---- P1: quadrant (qm=0, qn=1); needs B-half1 of tile t
    if (pf) { asm volatile("s_waitcnt vmcnt(4)" ::: "memory"); }
    else    { asm volatile("s_waitcnt vmcnt(2)" ::: "memory"); }
    __builtin_amdgcn_s_barrier();
#pragma unroll
    for (int n = 0; n < 2; ++n) { bf[n][0] = LDB_(cur, 1, n, 0); bf[n][1] = LDB_(cur, 1, n, 1); }
    if (pf) STAGE_B(nxt, 0, knext);
    __builtin_amdgcn_s_setprio(1);
#pragma unroll
    for (int m = 0; m < 4; ++m)
#pragma unroll
      for (int n = 0; n < 2; ++n) {
        acc[0][m][1][n] = __builtin_amdgcn_mfma_f32_16x16x32_f16(af[m][0], bf[n][0], acc[0][m][1][n], 0, 0, 0);
        acc[0][m][1][n] = __builtin_amdgcn_mfma_f32_16x16x32_f16(af[m][1], bf[n][1], acc[0][m][1][n], 0, 0, 0);
      }
    __builtin_amdgcn_s_setprio(0);

    // ---- P2: quadrant (qm=1, qn=1); needs A-half1 of tile t (bf reused)
    if (pf) { asm volatile("s_waitcnt vmcnt(4)" ::: "memory"); }
    else    { asm volatile("s_waitcnt vmcnt(0)" ::: "memory"); }
    __builtin_amdgcn_s_barrier();
#pragma unroll
    for (int m = 0; m < 4; ++m) { af[m][0] = LDA_(cur, 1, m, 0); af[m][1] = LDA_(cur, 1, m, 1); }
    if (pf) STAGE_B(nxt, 1, knext);
    __builtin_amdgcn_s_setprio(1);
#pragma unroll
    for (int m = 0; m < 4; ++m)
#pragma unroll
      for (int n = 0; n < 2; ++n) {
        acc[1][m][1][n] = __builtin_amdgcn_mfma_f32_16x16x32_f16(af[m][0], bf[n][0], acc[1][m][1][n], 0, 0, 0);
        acc[1][m][1][n] = __builtin_amdgcn_mfma_f32_16x16x32_f16(af[m][1], bf[n][1], acc[1][m][1][n], 0, 0, 0);
      }
    __builtin_amdgcn_s_setprio(0);

    // ---- P3: quadrant (qm=1, qn=0); re-reads B-half0 (landed since P0), af reused
    __builtin_amdgcn_s_barrier();
#pragma unroll
    for (int n = 0; n < 2; ++n) { bf[n][0] = LDB_(cur, 0, n, 0); bf[n][1] = LDB_(cur, 0, n, 1); }
    if (pf) STAGE_A(nxt, 1, knext);
    __builtin_amdgcn_s_setprio(1);
#pragma unroll
    for (int m = 0; m < 4; ++m)
#pragma unroll
      for (int n = 0; n < 2; ++n) {
        acc[1][m][0][n] = __builtin_amdgcn_mfma_f32_16x16x32_f16(af[m][0], bf[n][0], acc[1][m][0][n], 0, 0, 0);
        acc[1][m][0][n] = __builtin_amdgcn_mfma_f32_16x16x32_f16(af[m][1], bf[n][1], acc[1][m][0][n], 0, 0, 0);
      }
    __builtin_amdgcn_s_setprio(0);
  }

  // epilogue: C/D layout col=lane&15, row=(lane>>4)*4+j
  if (F32OUT) {
    float* dst = Cf + (long)ks * M * N;
#pragma unroll
    for (int qm = 0; qm < 2; ++qm)
#pragma unroll
    for (int m = 0; m < 4; ++m) {
      const long r0 = m0 + qm * 128 + wm * 64 + m * 16 + ls * 4;
#pragma unroll
      for (int qn = 0; qn < 2; ++qn)
#pragma unroll
      for (int n = 0; n < 2; ++n) {
        const long c = n0 + qn * 128 + wn * 32 + n * 16 + lh;
#pragma unroll
        for (int j = 0; j < 4; ++j)
          dst[(r0 + j) * N + c] = acc[qm][m][qn][n][j];
      }
    }
  } else {
#pragma unroll
    for (int qm = 0; qm < 2; ++qm)
#pragma unroll
    for (int m = 0; m < 4; ++m) {
      const long r0 = m0 + qm * 128 + wm * 64 + m * 16 + ls * 4;
#pragma unroll
      for (int qn = 0; qn < 2; ++qn)
#pragma unroll
      for (int n = 0; n < 2; ++n) {
        const long c = n0 + qn * 128 + wn * 32 + n * 16 + lh;
        const float bv = bias[c];
#pragma unroll
        for (int j = 0; j < 4; ++j)
          C[(r0 + j) * N + c] = (_Float16)(acc[qm][m][qn][n][j] + bv);
      }
    }
  }
#undef STAGE_A
#undef STAGE_B
#undef LDA_
#undef LDB_
}

// ---------------- split-K reduce: h = relu(p0 + p1 + bias) -> fp16 ----------------
__global__ __launch_bounds__(256) void k_redk(const float* __restrict__ P,
                                              const float* __restrict__ bias,
                                              _Float16* __restrict__ out, long MN4, int N) {
  long i = (long)blockIdx.x * 256 + threadIdx.x;
  if (i >= MN4) return;
  f4 a = ((const f4*)P)[i];
  f4 b = ((const f4*)P)[i + MN4];
  int col = (int)((i << 2) & (N - 1));
  f4 bb = *(const f4*)&bias[col];
  h4v o;
#pragma unroll
  for (int u = 0; u < 4; ++u) o[u] = (_Float16)fmaxf(a[u] + b[u] + bb[u], 0.f);
  ((h4v*)out)[i] = o;
}

// ---------------- block-diagonal GEMM2 ----------------
__global__ __launch_bounds__(256) void k_gemm2(const _Float16* __restrict__ out1,
                                               const float* __restrict__ fc2w,
                                               const float* __restrict__ fc2b,
                                               _Float16* __restrict__ out2) {
  const int b0 = (blockIdx.x >> 4) * 64;
  const int p  = (blockIdx.x & 15) * 32 + (threadIdx.x & 31);
  const int bsub = threadIdx.x >> 5;
  f4 bb0 = *(const f4*)&fc2b[p * 16 + 0];
  f4 bb1 = *(const f4*)&fc2b[p * 16 + 4];
  f4 bb2 = *(const f4*)&fc2b[p * 16 + 8];
  f4 bb3 = *(const f4*)&fc2b[p * 16 + 12];
  for (int r = 0; r < 8; ++r) {
    const int b = b0 + r * 8 + bsub;
    h8 qv = *(const h8*)&out1[(long)b * NP1 + p * 8];
    f4 a0 = bb0, a1 = bb1, a2 = bb2, a3 = bb3;
#pragma unroll
    for (int i = 0; i < 8; ++i) {
      const float qi = (float)qv[i];
      const f4* wr = (const f4*)&fc2w[(long)(p * 8 + i) * NP2 + p * 16];
      a0 += qi * wr[0]; a1 += qi * wr[1]; a2 += qi * wr[2]; a3 += qi * wr[3];
    }
    h8 o0, o1;
#pragma unroll
    for (int u = 0; u < 4; ++u) {
      o0[u] = (_Float16)a0[u]; o0[4 + u] = (_Float16)a1[u];
      o1[u] = (_Float16)a2[u]; o1[4 + u] = (_Float16)a3[u];
    }
    h8* dst = (h8*)&out2[(long)b * NP2 + p * 16];
    dst[0] = o0; dst[1] = o1;
  }
}

// ---------------- GEMM4 (f32) + sigmoid ----------------
__global__ __launch_bounds__(256) void k_logits(const _Float16* __restrict__ h,
                                                const float* __restrict__ w2,
                                                const float* __restrict__ b2,
                                                float* __restrict__ logits,
                                                float* __restrict__ hazards) {
  const int lane = threadIdx.x & 63;
  const int b = blockIdx.x * 4 + (threadIdx.x >> 6);
  f4 acc = {0.f, 0.f, 0.f, 0.f};
  const _Float16* hp = &h[(long)b * NH];
#pragma unroll
  for (int c4 = 0; c4 < 4; ++c4) {
    const int k0 = c4 * 512 + lane * 8;
    h8 hv = *(const h8*)&hp[k0];
#pragma unroll
    for (int u = 0; u < 8; ++u)
      acc += (float)hv[u] * *(const f4*)&w2[(long)(k0 + u) * 4];
  }
#pragma unroll
  for (int off = 32; off > 0; off >>= 1) {
#pragma unroll
    for (int u = 0; u < 4; ++u) acc[u] += __shfl_xor(acc[u], off, 64);
  }
  if (lane == 0) {
    f4 lg = acc + *(const f4*)b2;
    ((f4*)logits)[b] = lg;
    f4 hz;
#pragma unroll
    for (int u = 0; u < 4; ++u) hz[u] = 1.f / (1.f + expf(-lg[u]));
    ((f4*)hazards)[b] = hz;
  }
}

// ---------------- cumprod along batch + first-occurrence argmax ----------------
__global__ __launch_bounds__(256) void k_final(const float* __restrict__ logits,
                                               const float* __restrict__ hazards,
                                               float* __restrict__ S,
                                               float* __restrict__ yhat) {
  const int c = blockIdx.x;
  const int t = threadIdx.x;
  __shared__ float pl[256];
  __shared__ float mv[256];
  __shared__ int   mi[256];
  float prod = 1.f;
  float best = -1e30f; int bi = 0;
  for (int i = 0; i < 16; ++i) {
    const int b = t * 16 + i;
    prod *= (1.f - hazards[b * 4 + c]);
    const float lg = logits[b * 4 + c];
    if (lg > best) { best = lg; bi = b; }
  }
  pl[t] = prod; mv[t] = best; mi[t] = bi;
  __syncthreads();
  for (int off = 1; off < 256; off <<= 1) {
    float cur  = pl[t];
    float prev = (t >= off) ? pl[t - off] : 1.f;
    __syncthreads();
    pl[t] = cur * prev;
    __syncthreads();
  }
  float s = (t == 0) ? 1.f : pl[t - 1];
  for (int i = 0; i < 16; ++i) {
    const int b = t * 16 + i;
    s *= (1.f - hazards[b * 4 + c]);
    S[b * 4 + c] = s;
  }
  for (int off = 128; off > 0; off >>= 1) {
    if (t < off) {
      float ov = mv[t + off]; int oi = mi[t + off];
      if (ov > mv[t] || (ov == mv[t] && oi < mi[t])) { mv[t] = ov; mi[t] = oi; }
    }
    __syncthreads();
  }
  if (t == 0) yhat[c] = (float)mi[0];
}

extern "C" void kernel_launch(void* const* d_in, const int* in_sizes, int n_in,
                              void* d_out, int out_size, void* d_ws, size_t ws_size,
                              hipStream_t stream) {
  (void)in_sizes; (void)n_in; (void)out_size; (void)ws_size;
  const float* x    = (const float*)d_in[0];
  const float* fc1w = (const float*)d_in[1];
  const float* fc1b = (const float*)d_in[2];
  const float* fc2w = (const float*)d_in[3];
  const float* fc2b = (const float*)d_in[4];
  const float* w1   = (const float*)d_in[5];
  const float* b1   = (const float*)d_in[6];
  const float* w2   = (const float*)d_in[7];
  const float* b2   = (const float*)d_in[8];
  const int*   comp = (const int*)d_in[9];

  char* ws = (char*)d_ws;
  const size_t MB = 1024ull * 1024ull;
  // region plan (peak 160MB):
  //   [0,32M)    xh        -> dead after GEMM1 -> w1Th
  //   [32M,64M)  w1mT      -> dead after GEMM1 --\
  //   [64M,96M)  out1h     -> dead after GEMM2 ---> partials [32M,96M)
  //   [96M,160M) out2h     -> dead after GEMM3 -> hh [96M,112M), logits [112M,...)
  _Float16* xh     = (_Float16*)(ws + 0);
  _Float16* w1mT   = (_Float16*)(ws + 32 * MB);
  _Float16* out1h  = (_Float16*)(ws + 64 * MB);
  _Float16* out2h  = (_Float16*)(ws + 96 * MB);
  _Float16* w1Th   = (_Float16*)(ws + 0);
  float*    part   = (float*)(ws + 32 * MB);
  _Float16* hh     = (_Float16*)(ws + 96 * MB);
  float*    logits = (float*)(ws + 112 * MB);
  float*    outF   = (float*)d_out;

  hipFuncSetAttribute(reinterpret_cast<const void*>(k_gemm8<false>),
                      hipFuncAttributeMaxDynamicSharedMemorySize, 131072);
  hipFuncSetAttribute(reinterpret_cast<const void*>(k_gemm8<true>),
                      hipFuncAttributeMaxDynamicSharedMemorySize, 131072);

  // 1) pack x -> fp16
  k_pack_f16<<<(NB * NIN / 4) / 256, 256, 0, stream>>>(x, xh, NB * NIN / 4);
  // 2) pack (fc1_w * mask1)^T -> fp16 [P1][IN]
  k_packT<true><<<dim3(NP1 / 64, NIN / 64), 256, 0, stream>>>(fc1w, comp, w1mT, NIN, NP1);
  // 3) GEMM1: out1 = x @ fc1w_masked + fc1_b (256^2 8-phase)
  k_gemm8<false><<<(NB / 256) * (NP1 / 256), 512, 131072, stream>>>(
      xh, w1mT, fc1b, out1h, nullptr, NB, NP1, NIN, NP1 / 256, 1);
  // 4) block-diagonal GEMM2 -> out2 fp16
  k_gemm2<<<(NB / 64) * (NNP / 32), 256, 0, stream>>>(out1h, fc2w, fc2b, out2h);
  // 5) pack w1^T -> fp16 [H][P2] (overlays dead xh)
  k_packT<false><<<dim3(NH / 64, NP2 / 64), 256, 0, stream>>>(w1, nullptr, w1Th, NP2, NH);
  // 6) GEMM3 split-K=2: partials = out2 @ w1 (f32)
  k_gemm8<true><<<(NB / 256) * (NH / 256) * 2, 512, 131072, stream>>>(
      out2h, w1Th, nullptr, nullptr, part, NB, NH, NP2, NH / 256, 2);
  // 6b) h = relu(p0 + p1 + b1) -> fp16
  k_redk<<<(NB * NH / 4) / 256, 256, 0, stream>>>(part, b1, hh, (long)NB * NH / 4, NH);
  // 7) logits + hazards
  k_logits<<<NB / 4, 256, 0, stream>>>(hh, w2, b2, logits, outF);
  // 8) S and Y_hat
  k_final<<<4, 256, 0, stream>>>(logits, outF, outF + NB * 4, outF + 2 * NB * 4);
}